// Round 1
// baseline (256.744 us; speedup 1.0000x reference)
//
#include <hip/hip_runtime.h>
#include <hip/hip_bf16.h>

#define B_   4
#define S_   8192
#define D_   512
#define DFF_ 2048
#define K_TOP 1024

typedef unsigned short u16;
typedef __attribute__((ext_vector_type(8))) short bf16x8;
typedef __attribute__((ext_vector_type(4))) float floatx4;

// monotonic float -> uint key (order-preserving)
__device__ __forceinline__ unsigned f2key(float f){
    unsigned u = __float_as_uint(f);
    return (u & 0x80000000u) ? ~u : (u | 0x80000000u);
}
// fp32 -> bf16 round-to-nearest-even
__device__ __forceinline__ u16 f2b(float f){
    unsigned u = __float_as_uint(f);
    u = (u + 0x7FFFu + ((u >> 16) & 1u)) >> 16;
    return (u16)u;
}
__device__ __forceinline__ float gelu_tanh(float v){
    float c = 0.7978845608028654f * (v + 0.044715f * v * v * v);
    return 0.5f * v * (1.0f + tanhf(c));
}

// ---------------- kernel 1: router weights + x -> out passthrough ----------
__global__ __launch_bounds__(256) void wts_copy_kernel(
    const float4* __restrict__ x, float4* __restrict__ out,
    const float4* __restrict__ Wr4, const float* __restrict__ br,
    float* __restrict__ w_all)
{
    const int wv = threadIdx.x >> 6, lane = threadIdx.x & 63;
    const int token = blockIdx.x * 4 + wv;
    const float4* xt = x + (size_t)token * 128;
    float acc = 0.f;
    #pragma unroll
    for (int i = 0; i < 2; i++){
        int j = lane + i * 64;
        float4 v = xt[j];
        out[(size_t)token * 128 + j] = v;
        float4 wvv = Wr4[j];
        acc += v.x*wvv.x + v.y*wvv.y + v.z*wvv.z + v.w*wvv.w;
    }
    #pragma unroll
    for (int off = 32; off > 0; off >>= 1) acc += __shfl_down(acc, off, 64);
    if (lane == 0) w_all[token] = acc + br[0];
}

// ---------------- kernel 2: exact k-th largest per batch (radix select) ----
__global__ __launch_bounds__(256) void kth_kernel(
    const float* __restrict__ w_all, unsigned* __restrict__ thrkey,
    int* __restrict__ count)
{
    __shared__ unsigned hist[256];
    __shared__ unsigned sprefix;
    __shared__ int sremk;
    const int b = blockIdx.x, tid = threadIdx.x;
    const float* wrow = w_all + b * S_;
    if (tid == 0){ sprefix = 0u; sremk = K_TOP; if (b == 0) *count = 0; }
    __syncthreads();
    for (int pass = 3; pass >= 0; pass--){
        hist[tid] = 0u;
        __syncthreads();
        const unsigned mask_hi = (pass == 3) ? 0u : (0xFFFFFFFFu << ((pass + 1) * 8));
        const unsigned pfx = sprefix;
        const int shift = pass * 8;
        for (int i = tid; i < S_; i += 256){
            unsigned key = f2key(wrow[i]);
            if ((key & mask_hi) == pfx)
                atomicAdd(&hist[(key >> shift) & 255u], 1u);
        }
        __syncthreads();
        if (tid == 0){
            int rk = sremk; int bin = 255;
            while (bin > 0){
                unsigned c = hist[bin];
                if (c >= (unsigned)rk) break;
                rk -= (int)c; bin--;
            }
            sprefix = pfx | ((unsigned)bin << shift);
            sremk = rk;
        }
        __syncthreads();
    }
    if (tid == 0) thrkey[b] = sprefix;
}

// ---------------- kernel 3: compact selected token ids ---------------------
__global__ __launch_bounds__(256) void compact_kernel(
    const float* __restrict__ w_all, const unsigned* __restrict__ thrkey,
    int* __restrict__ count, int* __restrict__ idx)
{
    const int g = blockIdx.x * 256 + threadIdx.x;     // 0 .. B_*S_-1
    unsigned key = f2key(w_all[g]);
    if (key > thrkey[g >> 13]) {                      // strict >, key-space == value-space
        int p = atomicAdd(count, 1);
        idx[p] = g;
    }
}

// ---------------- kernel 4: transpose + fp32->bf16 convert of weights ------
// src: R x C fp32 (row-major) -> dst: C x R bf16 (row-major)
__global__ __launch_bounds__(256) void tconv_kernel(
    const float* __restrict__ src, u16* __restrict__ dst, int R, int C)
{
    __shared__ float tile[32][33];
    const int cb = blockIdx.x * 32, rb = blockIdx.y * 32;
    const int tr = threadIdx.x >> 5, tc = threadIdx.x & 31;
    #pragma unroll
    for (int i = 0; i < 4; i++){
        int r = tr + i * 8;
        tile[r][tc] = src[(size_t)(rb + r) * C + cb + tc];
    }
    __syncthreads();
    #pragma unroll
    for (int i = 0; i < 4; i++){
        int a = tr + i * 8;
        dst[(size_t)(cb + a) * R + rb + tc] = f2b(tile[tc][a]);
    }
}

// ---------------- kernel 5: GEMM1  H = gelu(Xsel @ W1 + b1)  (bf16 out) ----
// A: gathered x rows (fp32 -> bf16 on stage), B: W1bT [DFF_][D_] bf16
__global__ __launch_bounds__(256) void ffn1_kernel(
    const float* __restrict__ x, const int* __restrict__ idx,
    const int* __restrict__ countp, const u16* __restrict__ W1bT,
    const float* __restrict__ bias1, u16* __restrict__ H)
{
    __shared__ __align__(16) u16 As[64 * 40];
    __shared__ __align__(16) u16 Bs[64 * 40];
    const int tid = threadIdx.x;
    const int cnt = *countp;
    const int mBlk = blockIdx.x, nBlk = blockIdx.y;
    const int w = tid >> 6, lane = tid & 63;
    const int wm = (w >> 1) * 32, wn = (w & 1) * 32;
    const int fr = lane & 15, kq8 = (lane >> 4) * 8;

    const int sr = tid >> 2;            // 0..63 staged row
    const int sk = (tid & 3) * 8;       // 0,8,16,24
    const int mgs = mBlk * 64 + sr;
    const int arow = (mgs < cnt) ? idx[mgs] : 0;
    const float* aptr = x + (size_t)arow * D_ + sk;
    const u16* bptr = W1bT + (size_t)(nBlk * 64 + sr) * D_ + sk;

    floatx4 acc00 = {0,0,0,0}, acc01 = {0,0,0,0}, acc10 = {0,0,0,0}, acc11 = {0,0,0,0};

    for (int kt = 0; kt < D_; kt += 32){
        float4 v0 = *(const float4*)(aptr + kt);
        float4 v1 = *(const float4*)(aptr + kt + 4);
        bf16x8 av;
        av[0] = (short)f2b(v0.x); av[1] = (short)f2b(v0.y);
        av[2] = (short)f2b(v0.z); av[3] = (short)f2b(v0.w);
        av[4] = (short)f2b(v1.x); av[5] = (short)f2b(v1.y);
        av[6] = (short)f2b(v1.z); av[7] = (short)f2b(v1.w);
        *(bf16x8*)&As[sr * 40 + sk] = av;
        *(bf16x8*)&Bs[sr * 40 + sk] = *(const bf16x8*)(bptr + kt);
        __syncthreads();
        bf16x8 a0  = *(bf16x8*)&As[(wm + fr) * 40 + kq8];
        bf16x8 a1  = *(bf16x8*)&As[(wm + 16 + fr) * 40 + kq8];
        bf16x8 b0  = *(bf16x8*)&Bs[(wn + fr) * 40 + kq8];
        bf16x8 b1v = *(bf16x8*)&Bs[(wn + 16 + fr) * 40 + kq8];
        acc00 = __builtin_amdgcn_mfma_f32_16x16x32_bf16(a0, b0,  acc00, 0, 0, 0);
        acc01 = __builtin_amdgcn_mfma_f32_16x16x32_bf16(a0, b1v, acc01, 0, 0, 0);
        acc10 = __builtin_amdgcn_mfma_f32_16x16x32_bf16(a1, b0,  acc10, 0, 0, 0);
        acc11 = __builtin_amdgcn_mfma_f32_16x16x32_bf16(a1, b1v, acc11, 0, 0, 0);
        __syncthreads();
    }

    const int rbase = (lane >> 4) * 4;
    #pragma unroll
    for (int mi = 0; mi < 2; mi++){
        floatx4 aN0 = mi ? acc10 : acc00;
        floatx4 aN1 = mi ? acc11 : acc01;
        #pragma unroll
        for (int r = 0; r < 4; r++){
            int mg = mBlk * 64 + wm + mi * 16 + rbase + r;
            if (mg < cnt){
                int c0 = nBlk * 64 + wn + fr;
                int c1 = c0 + 16;
                H[(size_t)mg * DFF_ + c0] = f2b(gelu_tanh(aN0[r] + bias1[c0]));
                H[(size_t)mg * DFF_ + c1] = f2b(gelu_tanh(aN1[r] + bias1[c1]));
            }
        }
    }
}

// ---------------- kernel 6: GEMM2  out[token] = (H @ W2 + b2) * w ----------
// A: H rows bf16 (list order), B: W2bT [D_][DFF_] bf16
__global__ __launch_bounds__(256) void ffn2_kernel(
    const u16* __restrict__ H, const int* __restrict__ idx,
    const int* __restrict__ countp, const float* __restrict__ w_all,
    const u16* __restrict__ W2bT, const float* __restrict__ bias2,
    float* __restrict__ out)
{
    __shared__ __align__(16) u16 As[64 * 40];
    __shared__ __align__(16) u16 Bs[64 * 40];
    const int tid = threadIdx.x;
    const int cnt = *countp;
    const int mBlk = blockIdx.x, nBlk = blockIdx.y;
    const int w = tid >> 6, lane = tid & 63;
    const int wm = (w >> 1) * 32, wn = (w & 1) * 32;
    const int fr = lane & 15, kq8 = (lane >> 4) * 8;

    const int sr = tid >> 2;
    const int sk = (tid & 3) * 8;
    const u16* aptr = H + (size_t)(mBlk * 64 + sr) * DFF_ + sk;   // pad rows hold tiny poison, results discarded
    const u16* bptr = W2bT + (size_t)(nBlk * 64 + sr) * DFF_ + sk;

    floatx4 acc00 = {0,0,0,0}, acc01 = {0,0,0,0}, acc10 = {0,0,0,0}, acc11 = {0,0,0,0};

    for (int kt = 0; kt < DFF_; kt += 32){
        *(bf16x8*)&As[sr * 40 + sk] = *(const bf16x8*)(aptr + kt);
        *(bf16x8*)&Bs[sr * 40 + sk] = *(const bf16x8*)(bptr + kt);
        __syncthreads();
        bf16x8 a0  = *(bf16x8*)&As[(wm + fr) * 40 + kq8];
        bf16x8 a1  = *(bf16x8*)&As[(wm + 16 + fr) * 40 + kq8];
        bf16x8 b0  = *(bf16x8*)&Bs[(wn + fr) * 40 + kq8];
        bf16x8 b1v = *(bf16x8*)&Bs[(wn + 16 + fr) * 40 + kq8];
        acc00 = __builtin_amdgcn_mfma_f32_16x16x32_bf16(a0, b0,  acc00, 0, 0, 0);
        acc01 = __builtin_amdgcn_mfma_f32_16x16x32_bf16(a0, b1v, acc01, 0, 0, 0);
        acc10 = __builtin_amdgcn_mfma_f32_16x16x32_bf16(a1, b0,  acc10, 0, 0, 0);
        acc11 = __builtin_amdgcn_mfma_f32_16x16x32_bf16(a1, b1v, acc11, 0, 0, 0);
        __syncthreads();
    }

    const int rbase = (lane >> 4) * 4;
    #pragma unroll
    for (int mi = 0; mi < 2; mi++){
        floatx4 aN0 = mi ? acc10 : acc00;
        floatx4 aN1 = mi ? acc11 : acc01;
        #pragma unroll
        for (int r = 0; r < 4; r++){
            int mg = mBlk * 64 + wm + mi * 16 + rbase + r;
            if (mg < cnt){
                int token = idx[mg];
                float wt = w_all[token];
                int c0 = nBlk * 64 + wn + fr;
                int c1 = c0 + 16;
                out[(size_t)token * D_ + c0] = (aN0[r] + bias2[c0]) * wt;
                out[(size_t)token * D_ + c1] = (aN1[r] + bias2[c1]) * wt;
            }
        }
    }
}

extern "C" void kernel_launch(void* const* d_in, const int* in_sizes, int n_in,
                              void* d_out, int out_size, void* d_ws, size_t ws_size,
                              hipStream_t stream)
{
    const float* x  = (const float*)d_in[0];
    // d_in[1] = position_ids (unused by reference math)
    const float* Wr = (const float*)d_in[2];
    const float* br = (const float*)d_in[3];
    const float* W1 = (const float*)d_in[4];
    const float* b1 = (const float*)d_in[5];
    const float* W2 = (const float*)d_in[6];
    const float* b2 = (const float*)d_in[7];
    float* out = (float*)d_out;
    char* ws = (char*)d_ws;

    // workspace layout (bytes)
    float*    w_all  = (float*)   (ws + 0);         // 32768 f32
    unsigned* thrkey = (unsigned*)(ws + 131072);    // 4
    int*      count  = (int*)     (ws + 131088);    // 1
    int*      idx    = (int*)     (ws + 131104);    // 4096
    u16*      W1bT   = (u16*)     (ws + 262144);    // 2048 x 512 bf16
    u16*      W2bT   = (u16*)     (ws + 2359296);   // 512 x 2048 bf16
    u16*      H      = (u16*)     (ws + 4456448);   // 4096 x 2048 bf16

    tconv_kernel<<<dim3(DFF_/32, D_/32), 256, 0, stream>>>(W1, W1bT, D_, DFF_);
    tconv_kernel<<<dim3(D_/32, DFF_/32), 256, 0, stream>>>(W2, W2bT, DFF_, D_);
    wts_copy_kernel<<<(B_*S_)/4, 256, 0, stream>>>(
        (const float4*)x, (float4*)out, (const float4*)Wr, br, w_all);
    kth_kernel<<<B_, 256, 0, stream>>>(w_all, thrkey, count);
    compact_kernel<<<(B_*S_)/256, 256, 0, stream>>>(w_all, thrkey, count, idx);
    ffn1_kernel<<<dim3(64, DFF_/64), 256, 0, stream>>>(x, idx, count, W1bT, b1, H);
    ffn2_kernel<<<dim3(64, D_/64), 256, 0, stream>>>(H, idx, count, w_all, W2bT, b2, out);
}

// Round 2
// 212.868 us; speedup vs baseline: 1.2061x; 1.2061x over previous
//
#include <hip/hip_runtime.h>
#include <hip/hip_bf16.h>

#define B_   4
#define S_   8192
#define D_   512
#define DFF_ 2048
#define K_TOP 1024

typedef unsigned short u16;
typedef __attribute__((ext_vector_type(8))) short bf16x8;
typedef __attribute__((ext_vector_type(4))) float floatx4;

// monotonic float -> uint key (order-preserving)
__device__ __forceinline__ unsigned f2key(float f){
    unsigned u = __float_as_uint(f);
    return (u & 0x80000000u) ? ~u : (u | 0x80000000u);
}
// fp32 -> bf16 round-to-nearest-even
__device__ __forceinline__ u16 f2b(float f){
    unsigned u = __float_as_uint(f);
    u = (u + 0x7FFFu + ((u >> 16) & 1u)) >> 16;
    return (u16)u;
}
__device__ __forceinline__ float gelu_tanh(float v){
    float c = 0.7978845608028654f * (v + 0.044715f * v * v * v);
    return 0.5f * v * (1.0f + tanhf(c));
}

// ---------------- kernel 1: router weights + x -> out passthrough ----------
__global__ __launch_bounds__(256) void wts_copy_kernel(
    const float4* __restrict__ x, float4* __restrict__ out,
    const float4* __restrict__ Wr4, const float* __restrict__ br,
    float* __restrict__ w_all, int* __restrict__ count)
{
    if (blockIdx.x == 0 && threadIdx.x == 0) *count = 0;   // before kth in stream order
    const int wv = threadIdx.x >> 6, lane = threadIdx.x & 63;
    const int token = blockIdx.x * 4 + wv;
    const float4* xt = x + (size_t)token * 128;
    float acc = 0.f;
    #pragma unroll
    for (int i = 0; i < 2; i++){
        int j = lane + i * 64;
        float4 v = xt[j];
        out[(size_t)token * 128 + j] = v;
        float4 wvv = Wr4[j];
        acc += v.x*wvv.x + v.y*wvv.y + v.z*wvv.z + v.w*wvv.w;
    }
    #pragma unroll
    for (int off = 32; off > 0; off >>= 1) acc += __shfl_down(acc, off, 64);
    if (lane == 0) w_all[token] = acc + br[0];
}

// ------- kernel 2: exact k-th largest per batch (LDS radix select) + compact
// One block of 1024 threads per batch. All 8192 keys live in LDS; 4 radix
// passes over LDS; per-wave private histograms to cut atomic contention;
// parallel suffix-scan for bin selection; compaction fused at the end.
__global__ __launch_bounds__(1024) void kth_compact_kernel(
    const float4* __restrict__ w_all4, int* __restrict__ count,
    int* __restrict__ idx)
{
    __shared__ unsigned keys[S_];          // 32 KB
    __shared__ unsigned hist[16][256];     // 16 KB, per-wave private
    __shared__ unsigned suffix[256];
    __shared__ unsigned sprefix;
    __shared__ int sremk;
    const int b = blockIdx.x, tid = threadIdx.x, wv = tid >> 6;
    const float4* row4 = w_all4 + (size_t)b * (S_ / 4);

    #pragma unroll
    for (int i = 0; i < 2; i++){
        int j = tid + i * 1024;            // float4 index 0..2047
        float4 v = row4[j];
        keys[4*j+0] = f2key(v.x); keys[4*j+1] = f2key(v.y);
        keys[4*j+2] = f2key(v.z); keys[4*j+3] = f2key(v.w);
    }
    if (tid == 0){ sprefix = 0u; sremk = K_TOP; }
    __syncthreads();

    for (int pass = 3; pass >= 0; pass--){
        for (int i = tid; i < 16 * 256; i += 1024) ((unsigned*)hist)[i] = 0u;
        __syncthreads();
        const unsigned mask_hi = (pass == 3) ? 0u : (0xFFFFFFFFu << ((pass + 1) * 8));
        const unsigned pfx = sprefix;
        const int shift = pass * 8;
        #pragma unroll
        for (int i = 0; i < 8; i++){
            unsigned key = keys[tid + i * 1024];
            if ((key & mask_hi) == pfx)
                atomicAdd(&hist[wv][(key >> shift) & 255u], 1u);
        }
        __syncthreads();
        if (tid < 256){
            unsigned s = 0;
            #pragma unroll
            for (int h = 0; h < 16; h++) s += hist[h][tid];
            suffix[tid] = s;
        }
        __syncthreads();
        // inclusive reverse scan: suffix[t] = sum_{bin >= t} hist_total[bin]
        for (int off = 1; off < 256; off <<= 1){
            unsigned v = 0;
            if (tid < 256 && tid + off < 256) v = suffix[tid + off];
            __syncthreads();
            if (tid < 256) suffix[tid] += v;
            __syncthreads();
        }
        const int remk = sremk;            // read before the single writer updates
        __syncthreads();
        if (tid < 256){
            unsigned snext = (tid == 255) ? 0u : suffix[tid + 1];
            if (suffix[tid] >= (unsigned)remk && snext < (unsigned)remk){
                sprefix = pfx | ((unsigned)tid << shift);
                sremk = remk - (int)snext;
            }
        }
        __syncthreads();
    }

    const unsigned thr = sprefix;          // key of the k-th largest (exact)
    #pragma unroll
    for (int i = 0; i < 8; i++){
        int li = tid + i * 1024;
        if (keys[li] > thr){               // strict >, key-space == value-space
            int p = atomicAdd(count, 1);
            idx[p] = b * S_ + li;
        }
    }
}

// ---------------- kernel 4: transpose + fp32->bf16 convert of weights ------
// src: R x C fp32 (row-major) -> dst: C x R bf16 (row-major)
__global__ __launch_bounds__(256) void tconv_kernel(
    const float* __restrict__ src, u16* __restrict__ dst, int R, int C)
{
    __shared__ float tile[32][33];
    const int cb = blockIdx.x * 32, rb = blockIdx.y * 32;
    const int tr = threadIdx.x >> 5, tc = threadIdx.x & 31;
    #pragma unroll
    for (int i = 0; i < 4; i++){
        int r = tr + i * 8;
        tile[r][tc] = src[(size_t)(rb + r) * C + cb + tc];
    }
    __syncthreads();
    #pragma unroll
    for (int i = 0; i < 4; i++){
        int a = tr + i * 8;
        dst[(size_t)(cb + a) * R + rb + tc] = f2b(tile[tc][a]);
    }
}

// ---------------- kernel 5: GEMM1  H = gelu(Xsel @ W1 + b1)  (bf16 out) ----
__global__ __launch_bounds__(256) void ffn1_kernel(
    const float* __restrict__ x, const int* __restrict__ idx,
    const int* __restrict__ countp, const u16* __restrict__ W1bT,
    const float* __restrict__ bias1, u16* __restrict__ H)
{
    __shared__ __align__(16) u16 As[64 * 40];
    __shared__ __align__(16) u16 Bs[64 * 40];
    const int tid = threadIdx.x;
    const int cnt = *countp;
    const int mBlk = blockIdx.x, nBlk = blockIdx.y;
    const int w = tid >> 6, lane = tid & 63;
    const int wm = (w >> 1) * 32, wn = (w & 1) * 32;
    const int fr = lane & 15, kq8 = (lane >> 4) * 8;

    const int sr = tid >> 2;            // 0..63 staged row
    const int sk = (tid & 3) * 8;       // 0,8,16,24
    const int mgs = mBlk * 64 + sr;
    const int arow = (mgs < cnt) ? idx[mgs] : 0;
    const float* aptr = x + (size_t)arow * D_ + sk;
    const u16* bptr = W1bT + (size_t)(nBlk * 64 + sr) * D_ + sk;

    floatx4 acc00 = {0,0,0,0}, acc01 = {0,0,0,0}, acc10 = {0,0,0,0}, acc11 = {0,0,0,0};

    for (int kt = 0; kt < D_; kt += 32){
        float4 v0 = *(const float4*)(aptr + kt);
        float4 v1 = *(const float4*)(aptr + kt + 4);
        bf16x8 av;
        av[0] = (short)f2b(v0.x); av[1] = (short)f2b(v0.y);
        av[2] = (short)f2b(v0.z); av[3] = (short)f2b(v0.w);
        av[4] = (short)f2b(v1.x); av[5] = (short)f2b(v1.y);
        av[6] = (short)f2b(v1.z); av[7] = (short)f2b(v1.w);
        *(bf16x8*)&As[sr * 40 + sk] = av;
        *(bf16x8*)&Bs[sr * 40 + sk] = *(const bf16x8*)(bptr + kt);
        __syncthreads();
        bf16x8 a0  = *(bf16x8*)&As[(wm + fr) * 40 + kq8];
        bf16x8 a1  = *(bf16x8*)&As[(wm + 16 + fr) * 40 + kq8];
        bf16x8 b0  = *(bf16x8*)&Bs[(wn + fr) * 40 + kq8];
        bf16x8 b1v = *(bf16x8*)&Bs[(wn + 16 + fr) * 40 + kq8];
        acc00 = __builtin_amdgcn_mfma_f32_16x16x32_bf16(a0, b0,  acc00, 0, 0, 0);
        acc01 = __builtin_amdgcn_mfma_f32_16x16x32_bf16(a0, b1v, acc01, 0, 0, 0);
        acc10 = __builtin_amdgcn_mfma_f32_16x16x32_bf16(a1, b0,  acc10, 0, 0, 0);
        acc11 = __builtin_amdgcn_mfma_f32_16x16x32_bf16(a1, b1v, acc11, 0, 0, 0);
        __syncthreads();
    }

    const int rbase = (lane >> 4) * 4;
    #pragma unroll
    for (int mi = 0; mi < 2; mi++){
        floatx4 aN0 = mi ? acc10 : acc00;
        floatx4 aN1 = mi ? acc11 : acc01;
        #pragma unroll
        for (int r = 0; r < 4; r++){
            int mg = mBlk * 64 + wm + mi * 16 + rbase + r;
            if (mg < cnt){
                int c0 = nBlk * 64 + wn + fr;
                int c1 = c0 + 16;
                H[(size_t)mg * DFF_ + c0] = f2b(gelu_tanh(aN0[r] + bias1[c0]));
                H[(size_t)mg * DFF_ + c1] = f2b(gelu_tanh(aN1[r] + bias1[c1]));
            }
        }
    }
}

// ---------------- kernel 6: GEMM2  out[token] = (H @ W2 + b2) * w ----------
__global__ __launch_bounds__(256) void ffn2_kernel(
    const u16* __restrict__ H, const int* __restrict__ idx,
    const int* __restrict__ countp, const float* __restrict__ w_all,
    const u16* __restrict__ W2bT, const float* __restrict__ bias2,
    float* __restrict__ out)
{
    __shared__ __align__(16) u16 As[64 * 40];
    __shared__ __align__(16) u16 Bs[64 * 40];
    const int tid = threadIdx.x;
    const int cnt = *countp;
    const int mBlk = blockIdx.x, nBlk = blockIdx.y;
    const int w = tid >> 6, lane = tid & 63;
    const int wm = (w >> 1) * 32, wn = (w & 1) * 32;
    const int fr = lane & 15, kq8 = (lane >> 4) * 8;

    const int sr = tid >> 2;
    const int sk = (tid & 3) * 8;
    const u16* aptr = H + (size_t)(mBlk * 64 + sr) * DFF_ + sk;   // pad rows: results discarded
    const u16* bptr = W2bT + (size_t)(nBlk * 64 + sr) * DFF_ + sk;

    floatx4 acc00 = {0,0,0,0}, acc01 = {0,0,0,0}, acc10 = {0,0,0,0}, acc11 = {0,0,0,0};

    for (int kt = 0; kt < DFF_; kt += 32){
        *(bf16x8*)&As[sr * 40 + sk] = *(const bf16x8*)(aptr + kt);
        *(bf16x8*)&Bs[sr * 40 + sk] = *(const bf16x8*)(bptr + kt);
        __syncthreads();
        bf16x8 a0  = *(bf16x8*)&As[(wm + fr) * 40 + kq8];
        bf16x8 a1  = *(bf16x8*)&As[(wm + 16 + fr) * 40 + kq8];
        bf16x8 b0  = *(bf16x8*)&Bs[(wn + fr) * 40 + kq8];
        bf16x8 b1v = *(bf16x8*)&Bs[(wn + 16 + fr) * 40 + kq8];
        acc00 = __builtin_amdgcn_mfma_f32_16x16x32_bf16(a0, b0,  acc00, 0, 0, 0);
        acc01 = __builtin_amdgcn_mfma_f32_16x16x32_bf16(a0, b1v, acc01, 0, 0, 0);
        acc10 = __builtin_amdgcn_mfma_f32_16x16x32_bf16(a1, b0,  acc10, 0, 0, 0);
        acc11 = __builtin_amdgcn_mfma_f32_16x16x32_bf16(a1, b1v, acc11, 0, 0, 0);
        __syncthreads();
    }

    const int rbase = (lane >> 4) * 4;
    #pragma unroll
    for (int mi = 0; mi < 2; mi++){
        floatx4 aN0 = mi ? acc10 : acc00;
        floatx4 aN1 = mi ? acc11 : acc01;
        #pragma unroll
        for (int r = 0; r < 4; r++){
            int mg = mBlk * 64 + wm + mi * 16 + rbase + r;
            if (mg < cnt){
                int token = idx[mg];
                float wt = w_all[token];
                int c0 = nBlk * 64 + wn + fr;
                int c1 = c0 + 16;
                out[(size_t)token * D_ + c0] = (aN0[r] + bias2[c0]) * wt;
                out[(size_t)token * D_ + c1] = (aN1[r] + bias2[c1]) * wt;
            }
        }
    }
}

extern "C" void kernel_launch(void* const* d_in, const int* in_sizes, int n_in,
                              void* d_out, int out_size, void* d_ws, size_t ws_size,
                              hipStream_t stream)
{
    const float* x  = (const float*)d_in[0];
    // d_in[1] = position_ids (unused by reference math)
    const float* Wr = (const float*)d_in[2];
    const float* br = (const float*)d_in[3];
    const float* W1 = (const float*)d_in[4];
    const float* b1 = (const float*)d_in[5];
    const float* W2 = (const float*)d_in[6];
    const float* b2 = (const float*)d_in[7];
    float* out = (float*)d_out;
    char* ws = (char*)d_ws;

    // workspace layout (bytes)
    float*    w_all  = (float*)   (ws + 0);         // 32768 f32
    int*      count  = (int*)     (ws + 131088);    // 1
    int*      idx    = (int*)     (ws + 131104);    // 4096
    u16*      W1bT   = (u16*)     (ws + 262144);    // 2048 x 512 bf16
    u16*      W2bT   = (u16*)     (ws + 2359296);   // 512 x 2048 bf16
    u16*      H      = (u16*)     (ws + 4456448);   // 4096 x 2048 bf16

    tconv_kernel<<<dim3(DFF_/32, D_/32), 256, 0, stream>>>(W1, W1bT, D_, DFF_);
    tconv_kernel<<<dim3(D_/32, DFF_/32), 256, 0, stream>>>(W2, W2bT, DFF_, D_);
    wts_copy_kernel<<<(B_*S_)/4, 256, 0, stream>>>(
        (const float4*)x, (float4*)out, (const float4*)Wr, br, w_all, count);
    kth_compact_kernel<<<B_, 1024, 0, stream>>>((const float4*)w_all, count, idx);
    ffn1_kernel<<<dim3(64, DFF_/64), 256, 0, stream>>>(x, idx, count, W1bT, b1, H);
    ffn2_kernel<<<dim3(64, D_/64), 256, 0, stream>>>(H, idx, count, w_all, W2bT, b2, out);
}